// Round 1
// 698.738 us; speedup vs baseline: 1.3718x; 1.3718x over previous
//
#include <hip/hip_runtime.h>

#define B_    64
#define CIN_  3
#define J_    11
#define T_    512
#define CO_   128
#define KPS_  168
#define NLOC_ (B_*J_*T_)   // 360448
#define NSTATF_ 360448.0f

typedef unsigned short u16;
typedef unsigned int   u32;

typedef __attribute__((ext_vector_type(8))) short bh8;   // 8 bf16 = 4 VGPR (MFMA A/B frag)
typedef __attribute__((ext_vector_type(4))) float f32x4; // MFMA C/D frag

__device__ __forceinline__ float b2f(u16 u){ union{u32 i; float f;} v; v.i = ((u32)u)<<16; return v.f; }
__device__ __forceinline__ u16 f2b(float f){ union{float f; u32 i;} v; v.f=f; u32 r = v.i + 0x7FFFu + ((v.i>>16)&1u); return (u16)(r>>16); }
__device__ __forceinline__ u32 pk2(u16 a, u16 b){ return (u32)a | ((u32)b<<16); }

// load element i of an EXTERNAL buffer whose dtype is bf16 (BF=true) or fp32 (BF=false)
template<bool BF>
__device__ __forceinline__ float ldx(const void* p, size_t i){
  if constexpr (BF) return b2f(((const u16*)p)[i]);
  else              return ((const float*)p)[i];
}

// DT: detect external dtype from bit patterns of x (random N(0,1) data).
__global__ void kdet(const u32* __restrict__ xw, u32* __restrict__ flag){
  __shared__ int cnt;
  if (threadIdx.x==0) cnt=0;
  __syncthreads();
  u32 w = xw[threadIdx.x*4 + 1];
  int e = (int)((w>>7)&0xFFu);
  if (e>=100 && e<=140) atomicAdd(&cnt,1);
  __syncthreads();
  if (threadIdx.x==0) *flag = (cnt>128) ? 1u : 0u;   // 1 = bf16 I/O
}

// K0a: zero stat accumulators (dtype-free)
__global__ __launch_bounds__(256) void k0a_zero(float* __restrict__ statsY, float* __restrict__ statsF){
  const int stride = gridDim.x*blockDim.x;
  const int t0 = blockIdx.x*blockDim.x + threadIdx.x;
  for (int i=t0;i<64*512;i+=stride) statsY[i]=0.f;
  for (int i=t0;i<64*256;i+=stride) statsF[i]=0.f;
}

// K0b: transpose ps_w [128][168] -> psT [168][128] fp32, and build fusB:
// bf16 pre-swizzled LDS image of fus_w [o=128][k=256], 4 K-chunks of 16 KB.
// Within chunk kc: element (o, kk) at byte (o<<7)+(kk<<1), XOR-swizzled by ((o&7)<<4)
// so that MFMA ds_read_b128 fragment reads are bank-conflict-free.
template<bool BF>
__global__ __launch_bounds__(256) void k0b_tr(const u32* __restrict__ flag,
    const void* __restrict__ ps_w, const void* __restrict__ fus_w,
    float* __restrict__ psT, u16* __restrict__ fusB)
{
  if (*flag != (BF?1u:0u)) return;
  const int stride = gridDim.x*blockDim.x;
  const int t0 = blockIdx.x*blockDim.x + threadIdx.x;
  for (int i=t0;i<128*168;i+=stride){ int o=i/168, k=i-o*168; psT[k*128+o]=ldx<BF>(ps_w,i); }
  for (int i=t0;i<128*256;i+=stride){
    int o=i>>8, k=i&255;
    int kc=k>>6, kk=k&63;
    int byte=(o<<7)+(kk<<1); byte ^= ((o&7)<<4);
    fusB[(kc*16384 + byte)>>1] = f2b(ldx<BF>(fus_w,i));
  }
}

// one Chen step of the depth-3 signature, c=4, fully unrolled
__device__ __forceinline__ void sigstep(float* S1, float* S2, float* S3, const float* d){
  float e2[16];
  #pragma unroll
  for (int a=0;a<4;a++){
    #pragma unroll
    for (int b=0;b<4;b++) e2[a*4+b] = 0.5f*d[a]*d[b];
  }
  #pragma unroll
  for (int a=0;a<4;a++){
    float s1e = S1[a] + (1.0f/3.0f)*d[a];
    #pragma unroll
    for (int b=0;b<4;b++){
      #pragma unroll
      for (int c=0;c<4;c++){
        S3[a*16+b*4+c] += S2[a*4+b]*d[c] + s1e*e2[b*4+c];
      }
    }
  }
  #pragma unroll
  for (int a=0;a<4;a++){
    #pragma unroll
    for (int b=0;b<4;b++) S2[a*4+b] += S1[a]*d[b] + e2[a*4+b];
  }
  #pragma unroll
  for (int a=0;a<4;a++) S1[a] += d[a];
}

// K1: per 64-location tile (one (b,j), 64 consecutive t): signatures + x_conv + ps conv.
// Y (ws) is ALWAYS bf16 internally.
template<bool BF>
__global__ __launch_bounds__(256) void k1_sig_conv(const u32* __restrict__ flag,
    const void* __restrict__ x, const int* __restrict__ path,
    const void* __restrict__ raw_w, const void* __restrict__ raw_b,
    const void* __restrict__ ps_b, const float* __restrict__ psT,
    u16* __restrict__ Y, float* __restrict__ statsY,
    int locOff, int writeY, int doStats)
{
  if (*flag != (BF?1u:0u)) return;
  __shared__ float sig[KPS_*68];   // [168 sig-ch][64 locs + pad4]; aliased as reduction buf later
  __shared__ float xt[CIN_][70];   // temporal slice with halo 3 (edge-clamped)
  __shared__ float xs[CIN_][3][64];// spatial path joints
  __shared__ float rw[CO_*9];
  __shared__ float rb[CO_];
  __shared__ int   pj[3];

  const int tid = threadIdx.x;
  const int blk = blockIdx.x;
  const int lb  = locOff + blk*64;       // global location base
  const int lbl = blk*64;                // chunk-local location base (Y index)
  const int b   = lb / (J_*T_);
  const int j   = (lb / T_) % J_;
  const int t0  = lb % T_;
  const size_t xbase = (size_t)b*CIN_*J_*T_;

  if (tid < 3) pj[tid] = path[j*3 + tid];
  for (int idx=tid; idx<CIN_*70; idx+=256){
    int c=idx/70, u=idx-c*70;
    int t=t0+u-3; t = t<0?0:(t>T_-1?T_-1:t);
    xt[c][u] = ldx<BF>(x, xbase + (size_t)(c*J_+j)*T_ + t);
  }
  for (int idx=tid; idx<CO_*9; idx+=256) rw[idx]=ldx<BF>(raw_w, idx);
  if (tid < CO_) rb[tid]=ldx<BF>(raw_b, tid);
  __syncthreads();
  for (int idx=tid; idx<CIN_*3*64; idx+=256){
    int c=idx/192, p=(idx>>6)%3, tt=idx&63;
    xs[c][p][tt] = ldx<BF>(x, xbase + (size_t)(c*J_+pj[p])*T_ + t0 + tt);
  }
  __syncthreads();

  // phase B: signatures. wave0 = spatial (L=3), wave1 = temporal (L=7); wave-uniform
  if (tid < 128){
    const bool spf = tid < 64;
    const int  tt  = tid & 63;
    const int  L   = spf ? 3 : 7;
    const float dt = spf ? 0.5f : (1.0f/6.0f);
    float S1[4], S2[16], S3[64];
    #pragma unroll
    for (int i=0;i<4;i++)  S1[i]=0.f;
    #pragma unroll
    for (int i=0;i<16;i++) S2[i]=0.f;
    #pragma unroll
    for (int i=0;i<64;i++) S3[i]=0.f;
    float prv[3], d[4];
    for (int c=0;c<3;c++) prv[c] = spf ? xs[c][0][tt] : xt[c][tt];
    d[0]=0.f; d[1]=prv[0]; d[2]=prv[1]; d[3]=prv[2];
    sigstep(S1,S2,S3,d);
    for (int s=1;s<L;s++){
      d[0]=dt;
      for (int c=0;c<3;c++){ float cv = spf ? xs[c][s][tt] : xt[c][tt+s]; d[c+1]=cv-prv[c]; prv[c]=cv; }
      sigstep(S1,S2,S3,d);
    }
    const int sb = spf ? 0 : 84;
    #pragma unroll
    for (int i=0;i<4;i++)  sig[(sb+i)*68+tt]   = S1[i];
    #pragma unroll
    for (int i=0;i<16;i++) sig[(sb+4+i)*68+tt] = S2[i];
    #pragma unroll
    for (int i=0;i<64;i++) sig[(sb+20+i)*68+tt]= S3[i];
  }
  __syncthreads();

  const int tx = tid & 7;   // loc group: locs tx*8+i
  const int ty = tid >> 3;  // channel group: ch = ty*4+c
  // phase C: x_conv (1x3, zero pad on t)
  float accC[8][4];
  {
    float w[4][9], bia[4];
    #pragma unroll
    for (int c=0;c<4;c++){
      bia[c]=rb[ty*4+c];
      #pragma unroll
      for (int q=0;q<9;q++) w[c][q]=rw[(ty*4+c)*9+q];
    }
    #pragma unroll
    for (int i=0;i<8;i++){
      const int tl=tx*8+i, tg=t0+tl;
      float xv[9];
      #pragma unroll
      for (int cc=0;cc<3;cc++){
        #pragma unroll
        for (int kt=0;kt<3;kt++){
          float v = xt[cc][tl+2+kt];            // x[tg-1+kt], edge-clamped in LDS
          if ((tg==0 && kt==0) || (tg==T_-1 && kt==2)) v=0.f;  // conv uses ZERO pad
          xv[cc*3+kt]=v;
        }
      }
      #pragma unroll
      for (int c=0;c<4;c++){
        float s=bia[c];
        #pragma unroll
        for (int q=0;q<9;q++) s=fmaf(xv[q],w[c][q],s);
        accC[i][c]=s;
      }
    }
  }
  // phase D: ps conv (K=168) from sig LDS; 8 locs x 4 ch per thread
  float accD[8][4];
  #pragma unroll
  for (int i=0;i<8;i++){ accD[i][0]=0.f;accD[i][1]=0.f;accD[i][2]=0.f;accD[i][3]=0.f; }
  const float4* psT4 = reinterpret_cast<const float4*>(psT);
  #pragma unroll 2
  for (int k=0;k<KPS_;k++){
    float4 w4 = psT4[k*32 + ty];
    const float4* sp4 = reinterpret_cast<const float4*>(&sig[k*68 + tx*8]);
    float4 s0 = sp4[0], s1 = sp4[1];
    float sv[8] = {s0.x,s0.y,s0.z,s0.w,s1.x,s1.y,s1.z,s1.w};
    #pragma unroll
    for (int i=0;i<8;i++){
      accD[i][0]=fmaf(sv[i],w4.x,accD[i][0]);
      accD[i][1]=fmaf(sv[i],w4.y,accD[i][1]);
      accD[i][2]=fmaf(sv[i],w4.z,accD[i][2]);
      accD[i][3]=fmaf(sv[i],w4.w,accD[i][3]);
    }
  }
  #pragma unroll
  for (int c=0;c<4;c++){
    float pb=ldx<BF>(ps_b, ty*4+c);
    #pragma unroll
    for (int i=0;i<8;i++) accD[i][c]+=pb;
  }
  // stores: Y[loc][0..127]=x_conv, Y[loc][128..255]=ps conv (bf16, 8B packed)
  if (writeY){
    #pragma unroll
    for (int i=0;i<8;i++){
      u16* yp = Y + (size_t)(lbl + tx*8+i)*256;
      u32 v0=pk2(f2b(accC[i][0]),f2b(accC[i][1]));
      u32 v1=pk2(f2b(accC[i][2]),f2b(accC[i][3]));
      *reinterpret_cast<uint2*>(yp + ty*4) = make_uint2(v0,v1);
      u32 v2=pk2(f2b(accD[i][0]),f2b(accD[i][1]));
      u32 v3=pk2(f2b(accD[i][2]),f2b(accD[i][3]));
      *reinterpret_cast<uint2*>(yp + 128 + ty*4) = make_uint2(v2,v3);
    }
  }
  if (doStats){
    float sums[16];
    #pragma unroll
    for (int c=0;c<4;c++){
      float sC=0,qC=0,sD=0,qD=0;
      #pragma unroll
      for (int i=0;i<8;i++){
        float v=accC[i][c]; sC+=v; qC+=v*v;
        float u=accD[i][c]; sD+=u; qD+=u*u;
      }
      sums[c]=sC; sums[4+c]=qC; sums[8+c]=sD; sums[12+c]=qD;
    }
    __syncthreads();            // everyone done reading sig
    float* red = sig;           // alias: [ty32][tx8][16] = 4096 floats
    #pragma unroll
    for (int q=0;q<16;q++) red[(ty*8+tx)*16+q] = sums[q];
    __syncthreads();
    for (int e=tid*2; e<tid*2+2; e++){
      int tye=e>>4, q=e&15;
      float s=0.f;
      for (int t2=0;t2<8;t2++) s += red[(tye*8+t2)*16+q];
      int ch = (q<8) ? (tye*4+(q&3)) : (128 + tye*4+(q&3));
      int which = (q&7)>>2;
      atomicAdd(&statsY[(blk&63)*512 + ch*2 + which], s);
    }
  }
}

// K2: finalize 256-channel BN scale/shift for Y
template<bool BF>
__global__ __launch_bounds__(256) void k2_finY(const u32* __restrict__ flag,
    const float* __restrict__ statsY,
    const void* __restrict__ raw_g, const void* __restrict__ raw_beta,
    const void* __restrict__ ps_g,  const void* __restrict__ ps_beta,
    float* __restrict__ scaleY, float* __restrict__ shiftY)
{
  if (*flag != (BF?1u:0u)) return;
  int ch = threadIdx.x;
  float s=0.f,q=0.f;
  for (int slot=0;slot<64;slot++){ s+=statsY[slot*512+ch*2]; q+=statsY[slot*512+ch*2+1]; }
  float m = s/NSTATF_;
  float v = q/NSTATF_ - m*m; v = fmaxf(v,0.f);
  float r = rsqrtf(v + 1e-5f);
  float g  = (ch<128)? ldx<BF>(raw_g,ch)    : ldx<BF>(ps_g,ch-128);
  float be = (ch<128)? ldx<BF>(raw_beta,ch) : ldx<BF>(ps_beta,ch-128);
  scaleY[ch]=r*g; shiftY[ch]=be - m*r*g;
}

// K3: fus 1x1 conv as bf16 MFMA GEMM.
//   F[ch][loc] = W[ch][k] . A[k][loc],  A = relu(scaleY*Y + shiftY)  (hi/lo bf16 split)
// Tile: 128 ch x 128 locs per block, K=256 in 4 chunks of 64. 4 waves (2x2 of 64x64).
// MFMA 16x16x32_bf16: A-frag = W row-segment (contiguous k), B-frag = A^T row-segment
// (Y_lds stored [loc][k], contiguous k). D: col(lane&15)=loc -> coalesced t-writes.
// Both LDS tiles XOR-swizzled (byte ^= (row&7)<<4) -> ds_read_b128 <=2-way (free).
// LDS = 3*16KB + 2KB = 50 KB -> 3 blocks/CU.
template<bool BF>
__global__ __launch_bounds__(256,3) void k3_fus(const u32* __restrict__ flag,
    const u16* __restrict__ Y,
    const u16* __restrict__ fusB, const float* __restrict__ scaleY, const float* __restrict__ shiftY,
    const void* __restrict__ fus_b, void* __restrict__ F, float* __restrict__ statsF,
    int locOff)
{
  if (*flag != (BF?1u:0u)) return;
  __shared__ u16 sAhi[128*64];   // activations hi, [loc][kk] swizzled
  __shared__ u16 sAlo[128*64];   // activations lo (residual)
  __shared__ u16 sB  [128*64];   // weights chunk, [o][kk] swizzled (pre-swizzled image copy)
  __shared__ float sSc[256], sSh[256];

  const int tid = threadIdx.x, blk = blockIdx.x;
  const size_t loc0  = (size_t)locOff + (size_t)blk*128;   // global
  const size_t loc0l = (size_t)blk*128;                    // chunk-local (Y)
  const int lane = tid & 63, wid = tid >> 6;
  const int wm = wid >> 1, wn = wid & 1;       // wave -> (ch half, loc half)
  const int lrow = lane >> 4, lcol = lane & 15;

  sSc[tid] = scaleY[tid];
  sSh[tid] = shiftY[tid];

  f32x4 acc[4][4];
  #pragma unroll
  for (int mt=0;mt<4;mt++)
    #pragma unroll
    for (int nt=0;nt<4;nt++) acc[mt][nt] = (f32x4){0.f,0.f,0.f,0.f};

  __syncthreads();

  for (int kc=0;kc<4;kc++){
    const int kb = kc*64;
    // ---- stage A (BN+ReLU fused, hi/lo split): 128 locs x 64 ch, 4 passes
    #pragma unroll
    for (int p=0;p<4;p++){
      const int loc = p*32 + (tid>>3);
      const int c16 = tid & 7;
      const int ch0 = kb + c16*8;
      uint4 u = *reinterpret_cast<const uint4*>(Y + (loc0l+loc)*256 + ch0);
      float f[8];
      f[0]=b2f((u16)(u.x&0xffff)); f[1]=b2f((u16)(u.x>>16));
      f[2]=b2f((u16)(u.y&0xffff)); f[3]=b2f((u16)(u.y>>16));
      f[4]=b2f((u16)(u.z&0xffff)); f[5]=b2f((u16)(u.z>>16));
      f[6]=b2f((u16)(u.w&0xffff)); f[7]=b2f((u16)(u.w>>16));
      u16 hi[8], lo[8];
      #pragma unroll
      for (int jq=0;jq<8;jq++){
        float v = fmaxf(fmaf(f[jq], sSc[ch0+jq], sSh[ch0+jq]), 0.f);
        u16 h = f2b(v);
        hi[jq] = h;
        lo[jq] = f2b(v - b2f(h));
      }
      int byte = (loc<<7) + (c16<<4); byte ^= ((loc&7)<<4);
      *reinterpret_cast<uint4*>((char*)sAhi + byte) =
          make_uint4(pk2(hi[0],hi[1]),pk2(hi[2],hi[3]),pk2(hi[4],hi[5]),pk2(hi[6],hi[7]));
      *reinterpret_cast<uint4*>((char*)sAlo + byte) =
          make_uint4(pk2(lo[0],lo[1]),pk2(lo[2],lo[3]),pk2(lo[4],lo[5]),pk2(lo[6],lo[7]));
    }
    // ---- stage B: linear copy of pre-swizzled 16 KB weight image
    {
      const char* src = (const char*)(fusB + kc*8192);
      #pragma unroll
      for (int p=0;p<4;p++){
        int q16 = (p*256 + tid) << 4;
        *reinterpret_cast<uint4*>((char*)sB + q16) =
            *reinterpret_cast<const uint4*>(src + q16);
      }
    }
    __syncthreads();
    // ---- MFMA: per wave 4x4 tiles of 16x16, 2 k-steps, hi+lo
    #pragma unroll
    for (int ks=0;ks<2;ks++){
      const int kk2 = (ks*32 + lrow*8) << 1;   // byte offset of this lane's k-octet
      bh8 wf[4], yh[4], yl[4];
      #pragma unroll
      for (int mt=0;mt<4;mt++){
        int o = wm*64 + mt*16 + lcol;
        int byp = (o<<7) + kk2; byp ^= ((o&7)<<4);
        wf[mt] = *reinterpret_cast<const bh8*>((const char*)sB + byp);
      }
      #pragma unroll
      for (int nt=0;nt<4;nt++){
        int l = wn*64 + nt*16 + lcol;
        int byp = (l<<7) + kk2; byp ^= ((l&7)<<4);
        yh[nt] = *reinterpret_cast<const bh8*>((const char*)sAhi + byp);
        yl[nt] = *reinterpret_cast<const bh8*>((const char*)sAlo + byp);
      }
      #pragma unroll
      for (int mt=0;mt<4;mt++){
        #pragma unroll
        for (int nt=0;nt<4;nt++){
          acc[mt][nt] = __builtin_amdgcn_mfma_f32_16x16x32_bf16(wf[mt], yh[nt], acc[mt][nt], 0,0,0);
          acc[mt][nt] = __builtin_amdgcn_mfma_f32_16x16x32_bf16(wf[mt], yl[nt], acc[mt][nt], 0,0,0);
        }
      }
    }
    __syncthreads();
  }

  // ---- epilogue: bias, stats, write F (pre-BN, external dtype) in output layout
  // D mapping: ch = wm*64 + mt*16 + lrow*4 + r ; loc = wn*64 + nt*16 + lcol
  const int bb  = (int)(loc0/(J_*T_));
  const int jj  = (int)((loc0/T_)%J_);
  const int tt0 = (int)(loc0%T_);
  #pragma unroll
  for (int mt=0;mt<4;mt++){
    #pragma unroll
    for (int r=0;r<4;r++){
      const int ch = wm*64 + mt*16 + lrow*4 + r;
      const float fb = ldx<BF>(fus_b, ch);
      const size_t ro = ((size_t)(bb*128+ch)*J_ + jj)*T_ + tt0 + wn*64 + lcol;
      float s=0.f, q=0.f;
      #pragma unroll
      for (int nt=0;nt<4;nt++){
        float v = acc[mt][nt][r] + fb;
        s += v; q += v*v;
        if constexpr (BF){
          float vp = __shfl_xor(v, 1);
          if (!(lane&1)){
            *reinterpret_cast<u32*>((u16*)F + ro + nt*16) = pk2(f2b(v), f2b(vp));
          }
        } else {
          ((float*)F)[ro + nt*16] = v;
        }
      }
      // reduce over the 16 lanes of each quarter-wave group (same ch)
      s += __shfl_xor(s,1); s += __shfl_xor(s,2); s += __shfl_xor(s,4); s += __shfl_xor(s,8);
      q += __shfl_xor(q,1); q += __shfl_xor(q,2); q += __shfl_xor(q,4); q += __shfl_xor(q,8);
      if (lcol==0){
        atomicAdd(&statsF[(blk&63)*256 + ch*2 + 0], s);
        atomicAdd(&statsF[(blk&63)*256 + ch*2 + 1], q);
      }
    }
  }
}

// K4: finalize fus BN scale/shift
template<bool BF>
__global__ __launch_bounds__(256) void k4_finF(const u32* __restrict__ flag,
    const float* __restrict__ statsF,
    const void* __restrict__ fus_g, const void* __restrict__ fus_beta,
    float* __restrict__ scaleF, float* __restrict__ shiftF)
{
  if (*flag != (BF?1u:0u)) return;
  int ch = threadIdx.x;
  if (ch < 128){
    float s=0.f,q=0.f;
    for (int slot=0;slot<64;slot++){ s+=statsF[slot*256+ch*2]; q+=statsF[slot*256+ch*2+1]; }
    float m=s/NSTATF_;
    float v=fmaxf(q/NSTATF_-m*m,0.f);
    float r=rsqrtf(v+1e-5f);
    float g=ldx<BF>(fus_g,ch), be=ldx<BF>(fus_beta,ch);
    scaleF[ch]=r*g; shiftF[ch]=be - m*r*g;
  }
}

// K5: elementwise BN+ReLU in place on d_out (which holds pre-BN F).
template<bool BF>
__global__ __launch_bounds__(256) void k5_out(const u32* __restrict__ flag,
    const float* __restrict__ scaleF, const float* __restrict__ shiftF, void* __restrict__ out)
{
  if (*flag != (BF?1u:0u)) return;
  if constexpr (BF){
    size_t idx = ((size_t)blockIdx.x*256 + threadIdx.x)*8;
    int ch = (int)((idx/(J_*T_)) & 127);
    float sc = scaleF[ch], sh = shiftF[ch];
    u16* o16 = (u16*)out;
    uint4 u = *reinterpret_cast<const uint4*>(o16 + idx);
    u32 w[4] = {u.x,u.y,u.z,u.w};
    u32 o[4];
    #pragma unroll
    for (int q=0;q<4;q++){
      float v0=fmaxf(fmaf(b2f((u16)(w[q]&0xffff)),sc,sh),0.f);
      float v1=fmaxf(fmaf(b2f((u16)(w[q]>>16)),sc,sh),0.f);
      o[q]=pk2(f2b(v0),f2b(v1));
    }
    *reinterpret_cast<uint4*>(o16 + idx) = make_uint4(o[0],o[1],o[2],o[3]);
  } else {
    size_t idx = ((size_t)blockIdx.x*256 + threadIdx.x)*4;
    int ch = (int)((idx/(J_*T_)) & 127);
    float sc = scaleF[ch], sh = shiftF[ch];
    float* of = (float*)out;
    float4 v = *reinterpret_cast<const float4*>(of + idx);
    v.x=fmaxf(fmaf(v.x,sc,sh),0.f);
    v.y=fmaxf(fmaf(v.y,sc,sh),0.f);
    v.z=fmaxf(fmaf(v.z,sc,sh),0.f);
    v.w=fmaxf(fmaf(v.w,sc,sh),0.f);
    *reinterpret_cast<float4*>(of + idx) = v;
  }
}

extern "C" void kernel_launch(void* const* d_in, const int* in_sizes, int n_in,
                              void* d_out, int out_size, void* d_ws, size_t ws_size,
                              hipStream_t stream)
{
  const void* x        = d_in[0];
  const int*  path     = (const int*)d_in[1];
  const void* raw_w    = d_in[2];
  const void* raw_b    = d_in[3];
  const void* raw_g    = d_in[4];
  const void* raw_beta = d_in[5];
  const void* ps_w     = d_in[6];
  const void* ps_b     = d_in[7];
  const void* ps_g     = d_in[8];
  const void* ps_beta  = d_in[9];
  const void* fus_w    = d_in[10];
  const void* fus_b    = d_in[11];
  const void* fus_g    = d_in[12];
  const void* fus_beta = d_in[13];

  char* w = (char*)d_ws;
  u32*   flag   = (u32*)w;   w += 256;
  float* statsY = (float*)w; w += 64*512*4;
  float* statsF = (float*)w; w += 64*256*4;
  float* psT    = (float*)w; w += KPS_*128*4;
  u16*   fusB   = (u16*)w;   w += 256*128*2;
  float* scaleY = (float*)w; w += 1024;
  float* shiftY = (float*)w; w += 1024;
  float* scaleF = (float*)w; w += 512;
  float* shiftF = (float*)w; w += 512;
  size_t off = (size_t)(w - (char*)d_ws);
  off = (off + 255) & ~(size_t)255;
  u16* Y = (u16*)((char*)d_ws + off);
  size_t avail = (ws_size > off) ? (ws_size - off) : 0;

  // chunk Y (bf16, 184.5 MB full) over batch so it fits in ws: c in {1,2,4,...,64}
  const size_t Yfull = (size_t)NLOC_*256*2;
  int c = 1;
  while (c < 64 && Yfull/(size_t)c > avail) c <<= 1;
  const int chunkLoc = NLOC_ / c;

  kdet<<<dim3(1),dim3(256),0,stream>>>((const u32*)x, flag);
  k0a_zero<<<dim3(64),dim3(256),0,stream>>>(statsY, statsF);
  k0b_tr<false><<<dim3(64),dim3(256),0,stream>>>(flag, ps_w, fus_w, psT, fusB);
  k0b_tr<true ><<<dim3(64),dim3(256),0,stream>>>(flag, ps_w, fus_w, psT, fusB);

  // phase A: stats for all chunks; keep Y only for the last chunk
  for (int i=0;i<c;i++){
    int wy = (i==c-1)?1:0;
    k1_sig_conv<false><<<dim3(chunkLoc/64),dim3(256),0,stream>>>(flag, x, path, raw_w, raw_b, ps_b, psT, Y, statsY, i*chunkLoc, wy, 1);
    k1_sig_conv<true ><<<dim3(chunkLoc/64),dim3(256),0,stream>>>(flag, x, path, raw_w, raw_b, ps_b, psT, Y, statsY, i*chunkLoc, wy, 1);
  }
  k2_finY<false><<<dim3(1),dim3(256),0,stream>>>(flag, statsY, raw_g, raw_beta, ps_g, ps_beta, scaleY, shiftY);
  k2_finY<true ><<<dim3(1),dim3(256),0,stream>>>(flag, statsY, raw_g, raw_beta, ps_g, ps_beta, scaleY, shiftY);

  // phase B: consume last chunk's Y first, then recompute+consume the others
  k3_fus<false><<<dim3(chunkLoc/128),dim3(256),0,stream>>>(flag, Y, fusB, scaleY, shiftY, fus_b, d_out, statsF, (c-1)*chunkLoc);
  k3_fus<true ><<<dim3(chunkLoc/128),dim3(256),0,stream>>>(flag, Y, fusB, scaleY, shiftY, fus_b, d_out, statsF, (c-1)*chunkLoc);
  for (int i=0;i<c-1;i++){
    k1_sig_conv<false><<<dim3(chunkLoc/64),dim3(256),0,stream>>>(flag, x, path, raw_w, raw_b, ps_b, psT, Y, statsY, i*chunkLoc, 1, 0);
    k1_sig_conv<true ><<<dim3(chunkLoc/64),dim3(256),0,stream>>>(flag, x, path, raw_w, raw_b, ps_b, psT, Y, statsY, i*chunkLoc, 1, 0);
    k3_fus<false><<<dim3(chunkLoc/128),dim3(256),0,stream>>>(flag, Y, fusB, scaleY, shiftY, fus_b, d_out, statsF, i*chunkLoc);
    k3_fus<true ><<<dim3(chunkLoc/128),dim3(256),0,stream>>>(flag, Y, fusB, scaleY, shiftY, fus_b, d_out, statsF, i*chunkLoc);
  }
  k4_finF<false><<<dim3(1),dim3(256),0,stream>>>(flag, statsF, fus_g, fus_beta, scaleF, shiftF);
  k4_finF<true ><<<dim3(1),dim3(256),0,stream>>>(flag, statsF, fus_g, fus_beta, scaleF, shiftF);
  k5_out<false><<<dim3(NLOC_*128/(256*4)),dim3(256),0,stream>>>(flag, scaleF, shiftF, d_out);
  k5_out<true ><<<dim3(NLOC_*128/(256*8)),dim3(256),0,stream>>>(flag, scaleF, shiftF, d_out);
}

// Round 2
// 520.423 us; speedup vs baseline: 1.8419x; 1.3426x over previous
//
#include <hip/hip_runtime.h>

#define B_    64
#define CIN_  3
#define J_    11
#define T_    512
#define CO_   128
#define KPS_  168
#define KPAD_ 192
#define NLOC_ (B_*J_*T_)   // 360448
#define NSTATF_ 360448.0f

typedef unsigned short u16;
typedef unsigned int   u32;

typedef __attribute__((ext_vector_type(8))) short bh8;   // 8 bf16 = 4 VGPR (MFMA A/B frag)
typedef __attribute__((ext_vector_type(4))) float f32x4; // MFMA C/D frag

__device__ __forceinline__ float b2f(u16 u){ union{u32 i; float f;} v; v.i = ((u32)u)<<16; return v.f; }
__device__ __forceinline__ u16 f2b(float f){ union{float f; u32 i;} v; v.f=f; u32 r = v.i + 0x7FFFu + ((v.i>>16)&1u); return (u16)(r>>16); }
__device__ __forceinline__ u32 pk2(u16 a, u16 b){ return (u32)a | ((u32)b<<16); }

// load element i of an EXTERNAL buffer whose dtype is bf16 (BF=true) or fp32 (BF=false)
template<bool BF>
__device__ __forceinline__ float ldx(const void* p, size_t i){
  if constexpr (BF) return b2f(((const u16*)p)[i]);
  else              return ((const float*)p)[i];
}

// DT: detect external dtype from bit patterns of x (random N(0,1) data).
__global__ void kdet(const u32* __restrict__ xw, u32* __restrict__ flag){
  __shared__ int cnt;
  if (threadIdx.x==0) cnt=0;
  __syncthreads();
  u32 w = xw[threadIdx.x*4 + 1];
  int e = (int)((w>>7)&0xFFu);
  if (e>=100 && e<=140) atomicAdd(&cnt,1);
  __syncthreads();
  if (threadIdx.x==0) *flag = (cnt>128) ? 1u : 0u;   // 1 = bf16 I/O
}

// K0a: zero stat accumulators (dtype-free)
__global__ __launch_bounds__(256) void k0a_zero(float* __restrict__ statsY, float* __restrict__ statsF){
  const int stride = gridDim.x*blockDim.x;
  const int t0 = blockIdx.x*blockDim.x + threadIdx.x;
  for (int i=t0;i<64*512;i+=stride) statsY[i]=0.f;
  for (int i=t0;i<64*256;i+=stride) statsF[i]=0.f;
}

// K0b: build
//  psB : bf16 image of ps_w [o=128][kk=192], kk<84 -> k=kk (spatial), 96<=kk<180 -> k=kk-12
//        (temporal), pads zero. Row stride 384B, NOT swizzled (read from global).
//  fusB: bf16 pre-swizzled LDS image of fus_w [o=128][k=256], 4 K-chunks of 16 KB,
//        within chunk: byte (o<<7)+(kk<<1), XOR ((o&7)<<4).
template<bool BF>
__global__ __launch_bounds__(256) void k0b_tr(const u32* __restrict__ flag,
    const void* __restrict__ ps_w, const void* __restrict__ fus_w,
    u16* __restrict__ psB, u16* __restrict__ fusB)
{
  if (*flag != (BF?1u:0u)) return;
  const int stride = gridDim.x*blockDim.x;
  const int t0 = blockIdx.x*blockDim.x + threadIdx.x;
  for (int i=t0;i<128*KPAD_;i+=stride){
    int o=i/KPAD_, kk=i-o*KPAD_;
    int k = (kk<84) ? kk : ((kk>=96 && kk<180) ? kk-12 : -1);
    psB[i] = (k>=0) ? f2b(ldx<BF>(ps_w, (size_t)o*KPS_+k)) : (u16)0;
  }
  for (int i=t0;i<128*256;i+=stride){
    int o=i>>8, k=i&255;
    int kc=k>>6, kk=k&63;
    int byte=(o<<7)+(kk<<1); byte ^= ((o&7)<<4);
    fusB[(kc*16384 + byte)>>1] = f2b(ldx<BF>(fus_w,i));
  }
}

// one Chen step of the depth-3 signature, c=4, fully unrolled
__device__ __forceinline__ void sigstep(float* S1, float* S2, float* S3, const float* d){
  float e2[16];
  #pragma unroll
  for (int a=0;a<4;a++){
    #pragma unroll
    for (int b=0;b<4;b++) e2[a*4+b] = 0.5f*d[a]*d[b];
  }
  #pragma unroll
  for (int a=0;a<4;a++){
    float s1e = S1[a] + (1.0f/3.0f)*d[a];
    #pragma unroll
    for (int b=0;b<4;b++){
      #pragma unroll
      for (int c=0;c<4;c++){
        S3[a*16+b*4+c] += S2[a*4+b]*d[c] + s1e*e2[b*4+c];
      }
    }
  }
  #pragma unroll
  for (int a=0;a<4;a++){
    #pragma unroll
    for (int b=0;b<4;b++) S2[a*4+b] += S1[a]*d[b] + e2[a*4+b];
  }
  #pragma unroll
  for (int a=0;a<4;a++) S1[a] += d[a];
}

// K1: per 64-location tile (one (b,j), 64 consecutive t): signatures + x_conv + ps conv.
// Sig -> LDS as bf16 hi/lo [loc][192] (XOR-swizzled); ps conv = MFMA (hi/lo x bf16 W).
// Waves: two (parity-rotated) waves do signatures; the other two do x_conv.
// Y (ws) is ALWAYS bf16 internally.
template<bool BF>
__global__ __launch_bounds__(256) void k1_sig_conv(const u32* __restrict__ flag,
    const void* __restrict__ x, const int* __restrict__ path,
    const void* __restrict__ raw_w, const void* __restrict__ raw_b,
    const void* __restrict__ ps_b, const u16* __restrict__ psB,
    u16* __restrict__ Y, float* __restrict__ statsY,
    int locOff, int writeY, int doStats)
{
  if (*flag != (BF?1u:0u)) return;
  __shared__ u16 sAhi[64*KPAD_];    // sig hi, [loc][kk] swizzled (24.5 KB)
  __shared__ u16 sAlo[64*KPAD_];    // sig lo residual (24.5 KB)
  __shared__ float xt[CIN_][72];    // temporal slice with halo 3 (edge-clamped)
  __shared__ float xs[CIN_][3][64]; // spatial path joints
  __shared__ int   pj[3];

  const int tid = threadIdx.x;
  const int blk = blockIdx.x;
  const int lb  = locOff + blk*64;       // global location base
  const int lbl = blk*64;                // chunk-local location base (Y index)
  const int b   = lb / (J_*T_);
  const int j   = (lb / T_) % J_;
  const int t0  = lb % T_;
  const size_t xbase = (size_t)b*CIN_*J_*T_;

  if (tid < 3) pj[tid] = path[j*3 + tid];
  for (int idx=tid; idx<CIN_*70; idx+=256){
    int c=idx/70, u=idx-c*70;
    int t=t0+u-3; t = t<0?0:(t>T_-1?T_-1:t);
    xt[c][u] = ldx<BF>(x, xbase + (size_t)(c*J_+j)*T_ + t);
  }
  __syncthreads();
  for (int idx=tid; idx<CIN_*3*64; idx+=256){
    int c=idx/192, p=(idx>>6)%3, tt=idx&63;
    xs[c][p][tt] = ldx<BF>(x, xbase + (size_t)(c*J_+pj[p])*T_ + t0 + tt);
  }
  __syncthreads();

  const int lane = tid & 63, wid = tid >> 6;
  const int wid2 = wid ^ ((blk&1)<<1);   // parity-rotate sig waves across SIMDs

  if (wid2 < 2){
    // ---- phase B: signatures (one loc per lane). wid2==0 spatial L=3, ==1 temporal L=7
    const bool spf = (wid2==0);
    const int  tt  = lane;
    const int  L   = spf ? 3 : 7;
    const float dt = spf ? 0.5f : (1.0f/6.0f);
    float S1[4], S2[16], S3[64];
    #pragma unroll
    for (int i=0;i<4;i++)  S1[i]=0.f;
    #pragma unroll
    for (int i=0;i<16;i++) S2[i]=0.f;
    #pragma unroll
    for (int i=0;i<64;i++) S3[i]=0.f;
    float prv[3], d[4];
    for (int c=0;c<3;c++) prv[c] = spf ? xs[c][0][tt] : xt[c][tt];
    d[0]=0.f; d[1]=prv[0]; d[2]=prv[1]; d[3]=prv[2];
    sigstep(S1,S2,S3,d);
    for (int s=1;s<L;s++){
      d[0]=dt;
      for (int c=0;c<3;c++){ float cv = spf ? xs[c][s][tt] : xt[c][tt+s]; d[c+1]=cv-prv[c]; prv[c]=cv; }
      sigstep(S1,S2,S3,d);
    }
    // convert to bf16 hi/lo and write 12 x b128 chunks into [loc][192] swizzled rows.
    // spatial occupies kk 0..95 (84 sig + 12 zero pad), temporal kk 96..191.
    const int sb2 = spf ? 0 : 192;   // byte offset within row
    const int rowb = tt*(KPAD_*2);
    const int swz  = (tt&7)<<4;
    #pragma unroll
    for (int i=0;i<12;i++){
      u16 hv[8], lv[8];
      #pragma unroll
      for (int e=0;e<8;e++){
        const int idx = i*8+e;
        float v;
        if (idx<4) v=S1[idx]; else if (idx<20) v=S2[idx-4]; else if (idx<84) v=S3[idx-20]; else v=0.f;
        u16 h = f2b(v);
        hv[e]=h; lv[e]=f2b(v - b2f(h));
      }
      int byp = (rowb + sb2 + i*16) ^ swz;
      *reinterpret_cast<uint4*>((char*)sAhi + byp) =
          make_uint4(pk2(hv[0],hv[1]),pk2(hv[2],hv[3]),pk2(hv[4],hv[5]),pk2(hv[6],hv[7]));
      *reinterpret_cast<uint4*>((char*)sAlo + byp) =
          make_uint4(pk2(lv[0],lv[1]),pk2(lv[2],lv[3]),pk2(lv[4],lv[5]),pk2(lv[6],lv[7]));
    }
  } else {
    // ---- phase C: x_conv (1x3, zero pad on t) on the two non-sig waves.
    // nid in [0,128): handles 8 locs (tx) x 8 channels (ty2*4+c for cg in {0,1})
    const int nid = (wid2-2)*64 + lane;
    const int tx = nid & 7, ty2 = nid >> 3;   // ty2 in [0,16)
    #pragma unroll
    for (int cg=0; cg<2; cg++){
      const int chb = cg*64 + ty2*4;
      float w[4][9], bia[4];
      #pragma unroll
      for (int c=0;c<4;c++){
        bia[c]=ldx<BF>(raw_b, chb+c);
        #pragma unroll
        for (int q=0;q<9;q++) w[c][q]=ldx<BF>(raw_w, (size_t)(chb+c)*9+q);
      }
      float accC[8][4];
      #pragma unroll
      for (int i=0;i<8;i++){
        const int tl=tx*8+i, tg=t0+tl;
        float xv[9];
        #pragma unroll
        for (int cc=0;cc<3;cc++){
          #pragma unroll
          for (int kt=0;kt<3;kt++){
            float v = xt[cc][tl+2+kt];            // x[tg-1+kt], edge-clamped in LDS
            if ((tg==0 && kt==0) || (tg==T_-1 && kt==2)) v=0.f;  // conv uses ZERO pad
            xv[cc*3+kt]=v;
          }
        }
        #pragma unroll
        for (int c=0;c<4;c++){
          float s=bia[c];
          #pragma unroll
          for (int q=0;q<9;q++) s=fmaf(xv[q],w[c][q],s);
          accC[i][c]=s;
        }
      }
      if (writeY){
        #pragma unroll
        for (int i=0;i<8;i++){
          u16* yp = Y + (size_t)(lbl + tx*8+i)*256 + chb;
          *reinterpret_cast<uint2*>(yp) =
            make_uint2(pk2(f2b(accC[i][0]),f2b(accC[i][1])), pk2(f2b(accC[i][2]),f2b(accC[i][3])));
        }
      }
      if (doStats){
        #pragma unroll
        for (int c=0;c<4;c++){
          float s=0.f,q=0.f;
          #pragma unroll
          for (int i=0;i<8;i++){ float v=accC[i][c]; s+=v; q+=v*v; }
          s += __shfl_xor(s,1); s += __shfl_xor(s,2); s += __shfl_xor(s,4);
          q += __shfl_xor(q,1); q += __shfl_xor(q,2); q += __shfl_xor(q,4);
          if ((lane&7)==0){
            atomicAdd(&statsY[(blk&63)*512 + (chb+c)*2 + 0], s);
            atomicAdd(&statsY[(blk&63)*512 + (chb+c)*2 + 1], q);
          }
        }
      }
    }
  }
  __syncthreads();

  // ---- phase D: ps conv as MFMA. Per wave: 32 ch x 64 locs, K=192 (6 ksteps), hi+lo.
  // A-frag: psB rows (global, L1-hit). B-frag: sAhi/sAlo rows (swizzled).
  const int lrow = lane >> 4, lcol = lane & 15;
  f32x4 acc[2][4];
  #pragma unroll
  for (int mt=0;mt<2;mt++)
    #pragma unroll
    for (int nt=0;nt<4;nt++) acc[mt][nt] = (f32x4){0.f,0.f,0.f,0.f};

  #pragma unroll
  for (int ks=0;ks<6;ks++){
    const int kk2 = ks*64 + lrow*16;   // byte offset of this lane's k-octet
    bh8 wf[2], yh[4], yl[4];
    #pragma unroll
    for (int mt=0;mt<2;mt++){
      const int o = wid*32 + mt*16 + lcol;
      wf[mt] = *reinterpret_cast<const bh8*>((const char*)psB + o*(KPAD_*2) + kk2);
    }
    #pragma unroll
    for (int nt=0;nt<4;nt++){
      const int l = nt*16 + lcol;
      const int byp = (l*(KPAD_*2) + kk2) ^ ((l&7)<<4);
      yh[nt] = *reinterpret_cast<const bh8*>((const char*)sAhi + byp);
      yl[nt] = *reinterpret_cast<const bh8*>((const char*)sAlo + byp);
    }
    #pragma unroll
    for (int mt=0;mt<2;mt++){
      #pragma unroll
      for (int nt=0;nt<4;nt++){
        acc[mt][nt] = __builtin_amdgcn_mfma_f32_16x16x32_bf16(wf[mt], yh[nt], acc[mt][nt], 0,0,0);
        acc[mt][nt] = __builtin_amdgcn_mfma_f32_16x16x32_bf16(wf[mt], yl[nt], acc[mt][nt], 0,0,0);
      }
    }
  }

  // ---- phase D epilogue: bias, Y ps-half write, stats.
  // D mapping: ch = wid*32 + mt*16 + lrow*4 + r ; loc = nt*16 + lcol
  #pragma unroll
  for (int mt=0;mt<2;mt++){
    const int chb = wid*32 + mt*16 + lrow*4;
    float pb[4];
    #pragma unroll
    for (int r=0;r<4;r++) pb[r]=ldx<BF>(ps_b, chb+r);
    float sv[4]={0.f,0.f,0.f,0.f}, qv[4]={0.f,0.f,0.f,0.f};
    #pragma unroll
    for (int nt=0;nt<4;nt++){
      float v0=acc[mt][nt][0]+pb[0], v1=acc[mt][nt][1]+pb[1];
      float v2=acc[mt][nt][2]+pb[2], v3=acc[mt][nt][3]+pb[3];
      sv[0]+=v0; qv[0]+=v0*v0; sv[1]+=v1; qv[1]+=v1*v1;
      sv[2]+=v2; qv[2]+=v2*v2; sv[3]+=v3; qv[3]+=v3*v3;
      if (writeY){
        u16* yp = Y + (size_t)(lbl + nt*16+lcol)*256 + 128 + chb;
        *reinterpret_cast<uint2*>(yp) = make_uint2(pk2(f2b(v0),f2b(v1)), pk2(f2b(v2),f2b(v3)));
      }
    }
    if (doStats){
      #pragma unroll
      for (int r=0;r<4;r++){
        float s=sv[r], q=qv[r];
        s += __shfl_xor(s,1); s += __shfl_xor(s,2); s += __shfl_xor(s,4); s += __shfl_xor(s,8);
        q += __shfl_xor(q,1); q += __shfl_xor(q,2); q += __shfl_xor(q,4); q += __shfl_xor(q,8);
        if (lcol==0){
          const int ch = 128 + chb + r;
          atomicAdd(&statsY[(blk&63)*512 + ch*2 + 0], s);
          atomicAdd(&statsY[(blk&63)*512 + ch*2 + 1], q);
        }
      }
    }
  }
}

// K2: finalize 256-channel BN scale/shift for Y
template<bool BF>
__global__ __launch_bounds__(256) void k2_finY(const u32* __restrict__ flag,
    const float* __restrict__ statsY,
    const void* __restrict__ raw_g, const void* __restrict__ raw_beta,
    const void* __restrict__ ps_g,  const void* __restrict__ ps_beta,
    float* __restrict__ scaleY, float* __restrict__ shiftY)
{
  if (*flag != (BF?1u:0u)) return;
  int ch = threadIdx.x;
  float s=0.f,q=0.f;
  for (int slot=0;slot<64;slot++){ s+=statsY[slot*512+ch*2]; q+=statsY[slot*512+ch*2+1]; }
  float m = s/NSTATF_;
  float v = q/NSTATF_ - m*m; v = fmaxf(v,0.f);
  float r = rsqrtf(v + 1e-5f);
  float g  = (ch<128)? ldx<BF>(raw_g,ch)    : ldx<BF>(ps_g,ch-128);
  float be = (ch<128)? ldx<BF>(raw_beta,ch) : ldx<BF>(ps_beta,ch-128);
  scaleY[ch]=r*g; shiftY[ch]=be - m*r*g;
}

// K3: fus 1x1 conv as bf16 MFMA GEMM (hi/lo activation split). Unchanged from prev round.
template<bool BF>
__global__ __launch_bounds__(256,3) void k3_fus(const u32* __restrict__ flag,
    const u16* __restrict__ Y,
    const u16* __restrict__ fusB, const float* __restrict__ scaleY, const float* __restrict__ shiftY,
    const void* __restrict__ fus_b, void* __restrict__ F, float* __restrict__ statsF,
    int locOff)
{
  if (*flag != (BF?1u:0u)) return;
  __shared__ u16 sAhi[128*64];   // activations hi, [loc][kk] swizzled
  __shared__ u16 sAlo[128*64];   // activations lo (residual)
  __shared__ u16 sB  [128*64];   // weights chunk, [o][kk] swizzled (pre-swizzled image copy)
  __shared__ float sSc[256], sSh[256];

  const int tid = threadIdx.x, blk = blockIdx.x;
  const size_t loc0  = (size_t)locOff + (size_t)blk*128;   // global
  const size_t loc0l = (size_t)blk*128;                    // chunk-local (Y)
  const int lane = tid & 63, wid = tid >> 6;
  const int wm = wid >> 1, wn = wid & 1;       // wave -> (ch half, loc half)
  const int lrow = lane >> 4, lcol = lane & 15;

  sSc[tid] = scaleY[tid];
  sSh[tid] = shiftY[tid];

  f32x4 acc[4][4];
  #pragma unroll
  for (int mt=0;mt<4;mt++)
    #pragma unroll
    for (int nt=0;nt<4;nt++) acc[mt][nt] = (f32x4){0.f,0.f,0.f,0.f};

  __syncthreads();

  for (int kc=0;kc<4;kc++){
    const int kb = kc*64;
    // ---- stage A (BN+ReLU fused, hi/lo split): 128 locs x 64 ch, 4 passes
    #pragma unroll
    for (int p=0;p<4;p++){
      const int loc = p*32 + (tid>>3);
      const int c16 = tid & 7;
      const int ch0 = kb + c16*8;
      uint4 u = *reinterpret_cast<const uint4*>(Y + (loc0l+loc)*256 + ch0);
      float f[8];
      f[0]=b2f((u16)(u.x&0xffff)); f[1]=b2f((u16)(u.x>>16));
      f[2]=b2f((u16)(u.y&0xffff)); f[3]=b2f((u16)(u.y>>16));
      f[4]=b2f((u16)(u.z&0xffff)); f[5]=b2f((u16)(u.z>>16));
      f[6]=b2f((u16)(u.w&0xffff)); f[7]=b2f((u16)(u.w>>16));
      u16 hi[8], lo[8];
      #pragma unroll
      for (int jq=0;jq<8;jq++){
        float v = fmaxf(fmaf(f[jq], sSc[ch0+jq], sSh[ch0+jq]), 0.f);
        u16 h = f2b(v);
        hi[jq] = h;
        lo[jq] = f2b(v - b2f(h));
      }
      int byte = (loc<<7) + (c16<<4); byte ^= ((loc&7)<<4);
      *reinterpret_cast<uint4*>((char*)sAhi + byte) =
          make_uint4(pk2(hi[0],hi[1]),pk2(hi[2],hi[3]),pk2(hi[4],hi[5]),pk2(hi[6],hi[7]));
      *reinterpret_cast<uint4*>((char*)sAlo + byte) =
          make_uint4(pk2(lo[0],lo[1]),pk2(lo[2],lo[3]),pk2(lo[4],lo[5]),pk2(lo[6],lo[7]));
    }
    // ---- stage B: linear copy of pre-swizzled 16 KB weight image
    {
      const char* src = (const char*)(fusB + kc*8192);
      #pragma unroll
      for (int p=0;p<4;p++){
        int q16 = (p*256 + tid) << 4;
        *reinterpret_cast<uint4*>((char*)sB + q16) =
            *reinterpret_cast<const uint4*>(src + q16);
      }
    }
    __syncthreads();
    // ---- MFMA: per wave 4x4 tiles of 16x16, 2 k-steps, hi+lo
    #pragma unroll
    for (int ks=0;ks<2;ks++){
      const int kk2 = (ks*32 + lrow*8) << 1;   // byte offset of this lane's k-octet
      bh8 wf[4], yh[4], yl[4];
      #pragma unroll
      for (int mt=0;mt<4;mt++){
        int o = wm*64 + mt*16 + lcol;
        int byp = (o<<7) + kk2; byp ^= ((o&7)<<4);
        wf[mt] = *reinterpret_cast<const bh8*>((const char*)sB + byp);
      }
      #pragma unroll
      for (int nt=0;nt<4;nt++){
        int l = wn*64 + nt*16 + lcol;
        int byp = (l<<7) + kk2; byp ^= ((l&7)<<4);
        yh[nt] = *reinterpret_cast<const bh8*>((const char*)sAhi + byp);
        yl[nt] = *reinterpret_cast<const bh8*>((const char*)sAlo + byp);
      }
      #pragma unroll
      for (int mt=0;mt<4;mt++){
        #pragma unroll
        for (int nt=0;nt<4;nt++){
          acc[mt][nt] = __builtin_amdgcn_mfma_f32_16x16x32_bf16(wf[mt], yh[nt], acc[mt][nt], 0,0,0);
          acc[mt][nt] = __builtin_amdgcn_mfma_f32_16x16x32_bf16(wf[mt], yl[nt], acc[mt][nt], 0,0,0);
        }
      }
    }
    __syncthreads();
  }

  // ---- epilogue: bias, stats, write F (pre-BN, external dtype) in output layout
  const int bb  = (int)(loc0/(J_*T_));
  const int jj  = (int)((loc0/T_)%J_);
  const int tt0 = (int)(loc0%T_);
  #pragma unroll
  for (int mt=0;mt<4;mt++){
    #pragma unroll
    for (int r=0;r<4;r++){
      const int ch = wm*64 + mt*16 + lrow*4 + r;
      const float fb = ldx<BF>(fus_b, ch);
      const size_t ro = ((size_t)(bb*128+ch)*J_ + jj)*T_ + tt0 + wn*64 + lcol;
      float s=0.f, q=0.f;
      #pragma unroll
      for (int nt=0;nt<4;nt++){
        float v = acc[mt][nt][r] + fb;
        s += v; q += v*v;
        if constexpr (BF){
          float vp = __shfl_xor(v, 1);
          if (!(lane&1)){
            *reinterpret_cast<u32*>((u16*)F + ro + nt*16) = pk2(f2b(v), f2b(vp));
          }
        } else {
          ((float*)F)[ro + nt*16] = v;
        }
      }
      s += __shfl_xor(s,1); s += __shfl_xor(s,2); s += __shfl_xor(s,4); s += __shfl_xor(s,8);
      q += __shfl_xor(q,1); q += __shfl_xor(q,2); q += __shfl_xor(q,4); q += __shfl_xor(q,8);
      if (lcol==0){
        atomicAdd(&statsF[(blk&63)*256 + ch*2 + 0], s);
        atomicAdd(&statsF[(blk&63)*256 + ch*2 + 1], q);
      }
    }
  }
}

// K4: finalize fus BN scale/shift
template<bool BF>
__global__ __launch_bounds__(256) void k4_finF(const u32* __restrict__ flag,
    const float* __restrict__ statsF,
    const void* __restrict__ fus_g, const void* __restrict__ fus_beta,
    float* __restrict__ scaleF, float* __restrict__ shiftF)
{
  if (*flag != (BF?1u:0u)) return;
  int ch = threadIdx.x;
  if (ch < 128){
    float s=0.f,q=0.f;
    for (int slot=0;slot<64;slot++){ s+=statsF[slot*256+ch*2]; q+=statsF[slot*256+ch*2+1]; }
    float m=s/NSTATF_;
    float v=fmaxf(q/NSTATF_-m*m,0.f);
    float r=rsqrtf(v+1e-5f);
    float g=ldx<BF>(fus_g,ch), be=ldx<BF>(fus_beta,ch);
    scaleF[ch]=r*g; shiftF[ch]=be - m*r*g;
  }
}

// K5: elementwise BN+ReLU in place on d_out (which holds pre-BN F).
template<bool BF>
__global__ __launch_bounds__(256) void k5_out(const u32* __restrict__ flag,
    const float* __restrict__ scaleF, const float* __restrict__ shiftF, void* __restrict__ out)
{
  if (*flag != (BF?1u:0u)) return;
  if constexpr (BF){
    size_t idx = ((size_t)blockIdx.x*256 + threadIdx.x)*8;
    int ch = (int)((idx/(J_*T_)) & 127);
    float sc = scaleF[ch], sh = shiftF[ch];
    u16* o16 = (u16*)out;
    uint4 u = *reinterpret_cast<const uint4*>(o16 + idx);
    u32 w[4] = {u.x,u.y,u.z,u.w};
    u32 o[4];
    #pragma unroll
    for (int q=0;q<4;q++){
      float v0=fmaxf(fmaf(b2f((u16)(w[q]&0xffff)),sc,sh),0.f);
      float v1=fmaxf(fmaf(b2f((u16)(w[q]>>16)),sc,sh),0.f);
      o[q]=pk2(f2b(v0),f2b(v1));
    }
    *reinterpret_cast<uint4*>(o16 + idx) = make_uint4(o[0],o[1],o[2],o[3]);
  } else {
    size_t idx = ((size_t)blockIdx.x*256 + threadIdx.x)*4;
    int ch = (int)((idx/(J_*T_)) & 127);
    float sc = scaleF[ch], sh = shiftF[ch];
    float* of = (float*)out;
    float4 v = *reinterpret_cast<const float4*>(of + idx);
    v.x=fmaxf(fmaf(v.x,sc,sh),0.f);
    v.y=fmaxf(fmaf(v.y,sc,sh),0.f);
    v.z=fmaxf(fmaf(v.z,sc,sh),0.f);
    v.w=fmaxf(fmaf(v.w,sc,sh),0.f);
    *reinterpret_cast<float4*>(of + idx) = v;
  }
}

extern "C" void kernel_launch(void* const* d_in, const int* in_sizes, int n_in,
                              void* d_out, int out_size, void* d_ws, size_t ws_size,
                              hipStream_t stream)
{
  const void* x        = d_in[0];
  const int*  path     = (const int*)d_in[1];
  const void* raw_w    = d_in[2];
  const void* raw_b    = d_in[3];
  const void* raw_g    = d_in[4];
  const void* raw_beta = d_in[5];
  const void* ps_w     = d_in[6];
  const void* ps_b     = d_in[7];
  const void* ps_g     = d_in[8];
  const void* ps_beta  = d_in[9];
  const void* fus_w    = d_in[10];
  const void* fus_b    = d_in[11];
  const void* fus_g    = d_in[12];
  const void* fus_beta = d_in[13];

  char* w = (char*)d_ws;
  u32*   flag   = (u32*)w;   w += 256;
  float* statsY = (float*)w; w += 64*512*4;
  float* statsF = (float*)w; w += 64*256*4;
  u16*   psB    = (u16*)w;   w += 128*KPAD_*2;
  u16*   fusB   = (u16*)w;   w += 256*128*2;
  float* scaleY = (float*)w; w += 1024;
  float* shiftY = (float*)w; w += 1024;
  float* scaleF = (float*)w; w += 512;
  float* shiftF = (float*)w; w += 512;
  size_t off = (size_t)(w - (char*)d_ws);
  off = (off + 255) & ~(size_t)255;
  u16* Y = (u16*)((char*)d_ws + off);
  size_t avail = (ws_size > off) ? (ws_size - off) : 0;

  // chunk Y (bf16, 184.5 MB full) over batch so it fits in ws: c in {1,2,4,...,64}
  const size_t Yfull = (size_t)NLOC_*256*2;
  int c = 1;
  while (c < 64 && Yfull/(size_t)c > avail) c <<= 1;
  const int chunkLoc = NLOC_ / c;

  kdet<<<dim3(1),dim3(256),0,stream>>>((const u32*)x, flag);
  k0a_zero<<<dim3(64),dim3(256),0,stream>>>(statsY, statsF);
  k0b_tr<false><<<dim3(64),dim3(256),0,stream>>>(flag, ps_w, fus_w, psB, fusB);
  k0b_tr<true ><<<dim3(64),dim3(256),0,stream>>>(flag, ps_w, fus_w, psB, fusB);

  // phase A: stats for all chunks; keep Y only for the last chunk
  for (int i=0;i<c;i++){
    int wy = (i==c-1)?1:0;
    k1_sig_conv<false><<<dim3(chunkLoc/64),dim3(256),0,stream>>>(flag, x, path, raw_w, raw_b, ps_b, psB, Y, statsY, i*chunkLoc, wy, 1);
    k1_sig_conv<true ><<<dim3(chunkLoc/64),dim3(256),0,stream>>>(flag, x, path, raw_w, raw_b, ps_b, psB, Y, statsY, i*chunkLoc, wy, 1);
  }
  k2_finY<false><<<dim3(1),dim3(256),0,stream>>>(flag, statsY, raw_g, raw_beta, ps_g, ps_beta, scaleY, shiftY);
  k2_finY<true ><<<dim3(1),dim3(256),0,stream>>>(flag, statsY, raw_g, raw_beta, ps_g, ps_beta, scaleY, shiftY);

  // phase B: consume last chunk's Y first, then recompute+consume the others
  k3_fus<false><<<dim3(chunkLoc/128),dim3(256),0,stream>>>(flag, Y, fusB, scaleY, shiftY, fus_b, d_out, statsF, (c-1)*chunkLoc);
  k3_fus<true ><<<dim3(chunkLoc/128),dim3(256),0,stream>>>(flag, Y, fusB, scaleY, shiftY, fus_b, d_out, statsF, (c-1)*chunkLoc);
  for (int i=0;i<c-1;i++){
    k1_sig_conv<false><<<dim3(chunkLoc/64),dim3(256),0,stream>>>(flag, x, path, raw_w, raw_b, ps_b, psB, Y, statsY, i*chunkLoc, 1, 0);
    k1_sig_conv<true ><<<dim3(chunkLoc/64),dim3(256),0,stream>>>(flag, x, path, raw_w, raw_b, ps_b, psB, Y, statsY, i*chunkLoc, 1, 0);
    k3_fus<false><<<dim3(chunkLoc/128),dim3(256),0,stream>>>(flag, Y, fusB, scaleY, shiftY, fus_b, d_out, statsF, i*chunkLoc);
    k3_fus<true ><<<dim3(chunkLoc/128),dim3(256),0,stream>>>(flag, Y, fusB, scaleY, shiftY, fus_b, d_out, statsF, i*chunkLoc);
  }
  k4_finF<false><<<dim3(1),dim3(256),0,stream>>>(flag, statsF, fus_g, fus_beta, scaleF, shiftF);
  k4_finF<true ><<<dim3(1),dim3(256),0,stream>>>(flag, statsF, fus_g, fus_beta, scaleF, shiftF);
  k5_out<false><<<dim3(NLOC_*128/(256*4)),dim3(256),0,stream>>>(flag, scaleF, shiftF, d_out);
  k5_out<true ><<<dim3(NLOC_*128/(256*8)),dim3(256),0,stream>>>(flag, scaleF, shiftF, d_out);
}